// Round 8
// baseline (475.580 us; speedup 1.0000x reference)
//
#include <hip/hip_runtime.h>
#include <hip/hip_bf16.h>

// AdaConv2d: per-sample conv, kernel = base * mask[label[b]] (oc-indep mask).
// B=64, IC=OC=64, H=W=112, 3x3, pad 1. fp32 in/out.
//
// Round 7: same as round 6 (ws-precomputed channel-last bf16 Xt + fused bf16
// weights; LDS-free MFMA main kernel) with the ushort4 typedef renamed (bf4)
// -- it collided with HIP's built-in ushort4.

#define HH 112
#define WW 112
#define ICn 64
#define OCn 64
#define FUSE_EPOCH 9
#define NPIX (HH * WW)
#define YP 114

typedef __attribute__((ext_vector_type(8)))  short  short8;
typedef __attribute__((ext_vector_type(8)))  unsigned short bf8;
typedef __attribute__((ext_vector_type(4)))  unsigned short bf4;
typedef __attribute__((ext_vector_type(16))) float  f32x16;

#define XT_ELEMS ((size_t)64 * YP * YP * 64)
#define XT_BYTES (XT_ELEMS * 2)
#define WF_BYTES ((size_t)4 * 64 * 576 * 2)

static __device__ __forceinline__ unsigned short f2bf(float v) {
    __hip_bfloat16 hb = __float2bfloat16(v);
    return *reinterpret_cast<unsigned short*>(&hb);
}

// ---------------- fused weights: wf[d][oc][ck][tap][ic'] ----------------
__global__ __launch_bounds__(256)
void fuse_w_kernel(const float* __restrict__ kb, const float* __restrict__ km,
                   unsigned short* __restrict__ wf)
{
    int idx = blockIdx.x * 256 + threadIdx.x;
    if (idx >= 4 * 64 * 576) return;
    int ic_ = idx & 15;
    int r = idx >> 4;
    int t = r % 9; r /= 9;
    int ch = r & 3; r >>= 2;
    int oc = r & 63;
    int d = r >> 6;
    int ic = ch * 16 + ic_;
    wf[idx] = f2bf(kb[(oc * ICn + ic) * 9 + t] * km[(d * ICn + ic) * 9 + t]);
}

// ---------------- zero the halo of Xt ----------------
__global__ __launch_bounds__(256)
void pad_zero_kernel(unsigned short* __restrict__ Xt)
{
    const int b = blockIdx.x, tid = threadIdx.x;
    const size_t base = (size_t)b * YP * YP * 64;
    // rows y=0 and y=113 (full)
    for (int i = tid; i < YP * 64 / 8; i += 256) {
        *reinterpret_cast<bf8*>(Xt + base + (size_t)i * 8) = bf8{0,0,0,0,0,0,0,0};
        *reinterpret_cast<bf8*>(Xt + base + (size_t)113 * YP * 64 + (size_t)i * 8) = bf8{0,0,0,0,0,0,0,0};
    }
    // cols x=0 and x=113 for rows 1..112
    for (int i = tid; i < 112 * 2 * 8; i += 256) {
        int k = i & 7, col = (i >> 3) & 1, yp = 1 + (i >> 4);
        size_t off = base + ((size_t)yp * YP + col * 113) * 64 + (size_t)k * 8;
        *reinterpret_cast<bf8*>(Xt + off) = bf8{0,0,0,0,0,0,0,0};
    }
}

// ---------------- transpose x[b][ic][y][x] fp32 -> Xt[b][y+1][x+1][ic] bf16 ----
__global__ __launch_bounds__(256, 4)
void transpose_kernel(const float* __restrict__ x, unsigned short* __restrict__ Xt)
{
    __shared__ unsigned short T[56][68];   // 68 pad: low conflicts
    const int tid = threadIdx.x;
    const int xh = blockIdx.x;      // 0..1 -> x0 = 0,56
    const int y  = blockIdx.y;      // 0..111
    const int b  = blockIdx.z;      // 0..63
    const int x0 = xh * 56;

    for (int i = tid; i < 64 * 14; i += 256) {       // 64 ic x 14 float4
        int ic = i / 14, c4 = i - ic * 14;
        const float4* p = reinterpret_cast<const float4*>(
            x + (((size_t)b * ICn + ic) * HH + y) * WW + x0 + c4 * 4);
        float4 v = *p;
        T[c4 * 4 + 0][ic] = f2bf(v.x);
        T[c4 * 4 + 1][ic] = f2bf(v.y);
        T[c4 * 4 + 2][ic] = f2bf(v.z);
        T[c4 * 4 + 3][ic] = f2bf(v.w);
    }
    __syncthreads();
    for (int i = tid; i < 56 * 16; i += 256) {       // 56 x  x 16 bf4
        int xx = i >> 4, k = i & 15;
        bf4 w = *reinterpret_cast<bf4*>(&T[xx][k * 4]);
        *reinterpret_cast<bf4*>(
            Xt + (((size_t)b * YP + y + 1) * YP + (x0 + xx + 1)) * 64 + k * 4) = w;
    }
}

// ---------------- main: implicit GEMM, no LDS ----------------
__global__ __launch_bounds__(256, 2)
void adaconv_main(const unsigned short* __restrict__ Xt,
                  const unsigned short* __restrict__ wf,
                  const int* __restrict__ label,
                  const int* __restrict__ epoch,
                  float* __restrict__ out)
{
    const int tid  = threadIdx.x;
    const int b    = blockIdx.y;
    const int w    = tid >> 6;
    const int lane = tid & 63;
    const int ln   = lane & 31;
    const int h    = lane >> 5;

    int d = (epoch[0] >= FUSE_EPOCH) ? 0 : label[b];
    d &= 3;

    f32x16 acc[2][4];
    #pragma unroll
    for (int m = 0; m < 2; ++m)
        #pragma unroll
        for (int rj = 0; rj < 4; ++rj)
            #pragma unroll
            for (int k = 0; k < 16; ++k) acc[m][rj][k] = 0.f;

    int yy[4], xx[4];
    bool valid[4];
    #pragma unroll
    for (int rj = 0; rj < 4; ++rj) {
        int p = blockIdx.x * 512 + w * 128 + rj * 32 + ln;
        valid[rj] = (p < NPIX);
        int pc = valid[rj] ? p : (NPIX - 1);
        yy[rj] = pc / WW;
        xx[rj] = pc - yy[rj] * WW;
    }

    const bf8* Wv = reinterpret_cast<const bf8*>(wf) + (size_t)d * 64 * 72;
    // Wv index: (oc*4 + ck)*18 + t*2 + h
    const unsigned xtb = (unsigned)b * YP * YP;

    #pragma unroll
    for (int ck = 0; ck < 4; ++ck) {
        #pragma unroll
        for (int kh = 0; kh < 3; ++kh) {
            #pragma unroll
            for (int kw = 0; kw < 3; ++kw) {
                const int t = kh * 3 + kw;
                short8 a0 = *reinterpret_cast<const short8*>(&Wv[(ln * 4 + ck) * 18 + t * 2 + h]);
                short8 a1 = *reinterpret_cast<const short8*>(&Wv[((ln + 32) * 4 + ck) * 18 + t * 2 + h]);
                #pragma unroll
                for (int rj = 0; rj < 4; ++rj) {
                    unsigned off = ((xtb + (unsigned)(yy[rj] + kh) * YP + (unsigned)(xx[rj] + kw)) << 6)
                                   + ck * 16 + h * 8;
                    short8 bb = *reinterpret_cast<const short8*>(Xt + off);
                    acc[0][rj] = __builtin_amdgcn_mfma_f32_32x32x16_bf16(a0, bb, acc[0][rj], 0, 0, 0);
                    acc[1][rj] = __builtin_amdgcn_mfma_f32_32x32x16_bf16(a1, bb, acc[1][rj], 0, 0, 0);
                }
            }
        }
    }

    // store: oc = m*32 + (reg&3) + 8*(reg>>2) + 4*h ; col = pixel p
    #pragma unroll
    for (int m = 0; m < 2; ++m) {
        #pragma unroll
        for (int rj = 0; rj < 4; ++rj) {
            if (!valid[rj]) continue;
            int p = blockIdx.x * 512 + w * 128 + rj * 32 + ln;
            float* ob = out + ((size_t)b * OCn + m * 32 + 4 * h) * NPIX + p;
            #pragma unroll
            for (int reg = 0; reg < 16; ++reg) {
                int row = (reg & 3) + 8 * (reg >> 2);
                ob[(size_t)row * NPIX] = acc[m][rj][reg];
            }
        }
    }
}

// ---------------- fallback (round-5 structure, no ws) ----------------
#define ICP 24
#define WSTRIDE 152
__global__ __launch_bounds__(256, 2)
void adaconv_fallback(const float* __restrict__ x,
                      const float* __restrict__ kb,
                      const float* __restrict__ km,
                      const int* __restrict__ label,
                      const int* __restrict__ epoch,
                      float* __restrict__ out)
{
    __shared__ unsigned short Xs[18][34][ICP];
    __shared__ unsigned short Ws[64][WSTRIDE];

    const int tid = threadIdx.x;
    const int b   = blockIdx.y;
    const int bx  = blockIdx.x & 3;
    const int byy = blockIdx.x >> 2;
    const int x0 = bx * 32, y0 = byy * 16;

    int d = (epoch[0] >= FUSE_EPOCH) ? 0 : label[b];
    d &= 3;

    const int w    = tid >> 6;
    const int lane = tid & 63;
    const int ln   = lane & 31;
    const int h    = lane >> 5;

    f32x16 acc[2][4];
    #pragma unroll
    for (int m = 0; m < 2; ++m)
        #pragma unroll
        for (int j = 0; j < 4; ++j)
            #pragma unroll
            for (int k = 0; k < 16; ++k) acc[m][j][k] = 0.f;

    const float* xb = x + (size_t)b * ICn * HH * WW;

    for (int ck = 0; ck < 4; ++ck) {
        const int icb = ck * 16;
        __syncthreads();
        for (int idx = tid; idx < 18 * 34 * 16; idx += 256) {
            int ic  = idx / 612;
            int rem = idx - ic * 612;
            int r   = rem / 34;
            int c   = rem - r * 34;
            int gy = y0 - 1 + r, gx = x0 - 1 + c;
            float v = 0.f;
            if ((unsigned)gy < HH && (unsigned)gx < WW)
                v = xb[(size_t)(icb + ic) * (HH * WW) + gy * WW + gx];
            Xs[r][c][ic] = f2bf(v);
        }
        for (int i = tid; i < 9216; i += 256) {
            int ic_ = i & 15;
            int tt  = (i >> 4) % 9;
            int oc  = i / 144;
            int ic  = icb + ic_;
            Ws[oc][tt * 16 + ic_] = f2bf(kb[(oc * ICn + ic) * 9 + tt] * km[(d * ICn + ic) * 9 + tt]);
        }
        __syncthreads();
        #pragma unroll
        for (int kh = 0; kh < 3; ++kh)
            #pragma unroll
            for (int kw = 0; kw < 3; ++kw) {
                const int t = kh * 3 + kw;
                short8 a0 = *reinterpret_cast<const short8*>(&Ws[ln][t * 16 + h * 8]);
                short8 a1 = *reinterpret_cast<const short8*>(&Ws[32 + ln][t * 16 + h * 8]);
                #pragma unroll
                for (int rj = 0; rj < 4; ++rj) {
                    short8 bb = *reinterpret_cast<const short8*>(&Xs[4 * w + rj + kh][ln + kw][h * 8]);
                    acc[0][rj] = __builtin_amdgcn_mfma_f32_32x32x16_bf16(a0, bb, acc[0][rj], 0, 0, 0);
                    acc[1][rj] = __builtin_amdgcn_mfma_f32_32x32x16_bf16(a1, bb, acc[1][rj], 0, 0, 0);
                }
            }
    }

    const int xg = x0 + ln;
    if (xg < WW) {
        #pragma unroll
        for (int m = 0; m < 2; ++m)
            #pragma unroll
            for (int rj = 0; rj < 4; ++rj) {
                const int yg = y0 + 4 * w + rj;
                #pragma unroll
                for (int reg = 0; reg < 16; ++reg) {
                    const int row = (reg & 3) + 8 * (reg >> 2) + 4 * h;
                    out[(((size_t)b * OCn + m * 32 + row) * HH + yg) * WW + xg] = acc[m][rj][reg];
                }
            }
    }
}

extern "C" void kernel_launch(void* const* d_in, const int* in_sizes, int n_in,
                              void* d_out, int out_size, void* d_ws, size_t ws_size,
                              hipStream_t stream) {
    const float* x  = (const float*)d_in[0];
    const float* kb = (const float*)d_in[1];
    const float* km = (const float*)d_in[2];
    const int*   lb = (const int*)d_in[3];
    const int*   ep = (const int*)d_in[4];
    float* out = (float*)d_out;

    if (ws_size >= XT_BYTES + WF_BYTES) {
        unsigned short* Xt = (unsigned short*)d_ws;
        unsigned short* wf = (unsigned short*)((char*)d_ws + XT_BYTES);
        fuse_w_kernel<<<(4 * 64 * 576 + 255) / 256, 256, 0, stream>>>(kb, km, wf);
        pad_zero_kernel<<<64, 256, 0, stream>>>(Xt);
        transpose_kernel<<<dim3(2, HH, 64), 256, 0, stream>>>(x, Xt);
        adaconv_main<<<dim3(25, 64), 256, 0, stream>>>(Xt, wf, lb, ep, out);
    } else {
        adaconv_fallback<<<dim3(28, 64), 256, 0, stream>>>(x, kb, km, lb, ep, out);
    }
}